// Round 1
// baseline (699.103 us; speedup 1.0000x reference)
//
#include <hip/hip_runtime.h>
#include <math.h>

#define SS 160
#define DD 512
#define HH 8
#define WDIM 64
#define MTOK 640
#define FFD 2048

// ---------------- embedding + LN0 ----------------
__global__ __launch_bounds__(256) void embed_ln0_kernel(
    const int* __restrict__ x, const int* __restrict__ stamp,
    const float* __restrict__ tok, const float* __restrict__ month,
    const float* __restrict__ day, const float* __restrict__ g0,
    const float* __restrict__ b0, float* __restrict__ h)
{
  int m = blockIdx.x; int b = m / SS; int s = m % SS; int t = threadIdx.x;
  int tokid = x[m];
  float v0 = tok[tokid*DD + t];
  float v1 = tok[tokid*DD + t + 256];
  if (s > 0) {
    int sidx = (b*(SS-1) + (s-1))*3;
    int mo = stamp[sidx+0], dy = stamp[sidx+1];
    v0 += month[mo*DD+t]     + day[dy*DD+t];
    v1 += month[mo*DD+t+256] + day[dy*DD+t+256];
  }
  float sum = v0+v1, sq = v0*v0+v1*v1;
  #pragma unroll
  for (int off=1; off<64; off<<=1) {
    sum += __shfl_xor(sum, off);
    sq  += __shfl_xor(sq , off);
  }
  __shared__ float ssh[4], qsh[4];
  if ((t&63)==0) { ssh[t>>6]=sum; qsh[t>>6]=sq; }
  __syncthreads();
  float fsum = ssh[0]+ssh[1]+ssh[2]+ssh[3];
  float fsq  = qsh[0]+qsh[1]+qsh[2]+qsh[3];
  float u = fsum * (1.0f/512.0f);
  float var = fsq * (1.0f/512.0f) - u*u;
  float r = rsqrtf(var + 1e-12f);
  h[m*DD+t]     = g0[t]    *((v0-u)*r) + b0[t];
  h[m*DD+t+256] = g0[t+256]*((v1-u)*r) + b0[t+256];
}

// ---------------- plain LayerNorm ----------------
__global__ __launch_bounds__(256) void ln_kernel(
    const float* __restrict__ in, const float* __restrict__ g,
    const float* __restrict__ b, float* __restrict__ out)
{
  int m = blockIdx.x; int t = threadIdx.x;
  float v0 = in[m*DD + t];
  float v1 = in[m*DD + t + 256];
  float sum = v0+v1, sq = v0*v0+v1*v1;
  #pragma unroll
  for (int off=1; off<64; off<<=1) {
    sum += __shfl_xor(sum, off);
    sq  += __shfl_xor(sq , off);
  }
  __shared__ float ssh[4], qsh[4];
  if ((t&63)==0) { ssh[t>>6]=sum; qsh[t>>6]=sq; }
  __syncthreads();
  float fsum = ssh[0]+ssh[1]+ssh[2]+ssh[3];
  float fsq  = qsh[0]+qsh[1]+qsh[2]+qsh[3];
  float u = fsum * (1.0f/512.0f);
  float var = fsq * (1.0f/512.0f) - u*u;
  float r = rsqrtf(var + 1e-12f);
  out[m*DD+t]     = g[t]    *((v0-u)*r) + b[t];
  out[m*DD+t+256] = g[t+256]*((v1-u)*r) + b[t+256];
}

// ---------------- tiled GEMM with epilogues ----------------
// C[M,N] = A[M,K] @ W[K,N] + bias[N]  (+resid)  (gelu)
#define EPI_NONE 0
#define EPI_RESID 1
#define EPI_GELU 2

template<int EPI>
__global__ __launch_bounds__(256) void gemm_ep(
    const float* __restrict__ A, const float* __restrict__ W,
    const float* __restrict__ bias, const float* __restrict__ resid,
    float* __restrict__ C, int M, int N, int K)
{
  __shared__ float As[16][68];   // [k][m], row stride 272B (16B aligned)
  __shared__ float Bs[16][68];   // [k][n]
  int tid = threadIdx.x;
  int m0 = blockIdx.y * 64, n0 = blockIdx.x * 64;
  int tr = tid >> 4, tc = tid & 15;
  int arow = tid >> 2, acol = (tid & 3) * 4;
  int wrow = tid >> 4, wcol = (tid & 15) * 4;
  float acc[4][4] = {};
  for (int k0 = 0; k0 < K; k0 += 16) {
    float4 a = *(const float4*)&A[(size_t)(m0+arow)*K + k0 + acol];
    As[acol+0][arow] = a.x; As[acol+1][arow] = a.y;
    As[acol+2][arow] = a.z; As[acol+3][arow] = a.w;
    *(float4*)&Bs[wrow][wcol] = *(const float4*)&W[(size_t)(k0+wrow)*N + n0 + wcol];
    __syncthreads();
    #pragma unroll
    for (int k = 0; k < 16; ++k) {
      float4 av = *(const float4*)&As[k][tr*4];
      float4 bv = *(const float4*)&Bs[k][tc*4];
      acc[0][0] += av.x*bv.x; acc[0][1] += av.x*bv.y; acc[0][2] += av.x*bv.z; acc[0][3] += av.x*bv.w;
      acc[1][0] += av.y*bv.x; acc[1][1] += av.y*bv.y; acc[1][2] += av.y*bv.z; acc[1][3] += av.y*bv.w;
      acc[2][0] += av.z*bv.x; acc[2][1] += av.z*bv.y; acc[2][2] += av.z*bv.z; acc[2][3] += av.z*bv.w;
      acc[3][0] += av.w*bv.x; acc[3][1] += av.w*bv.y; acc[3][2] += av.w*bv.z; acc[3][3] += av.w*bv.w;
    }
    __syncthreads();
  }
  #pragma unroll
  for (int i = 0; i < 4; ++i) {
    int m = m0 + tr*4 + i;
    int n = n0 + tc*4;
    float4 r;
    float vv[4];
    #pragma unroll
    for (int j = 0; j < 4; ++j) {
      float c = acc[i][j] + bias[n+j];
      if (EPI == EPI_RESID) c += resid[(size_t)m*N + n + j];
      if (EPI == EPI_GELU)  c = 0.5f*c*(1.0f + erff(c*0.70710678118654752f));
      vv[j] = c;
    }
    r.x = vv[0]; r.y = vv[1]; r.z = vv[2]; r.w = vv[3];
    *(float4*)&C[(size_t)m*N + n] = r;
  }
}

// ---------------- fused attention (one block per (i,h,b)) ----------------
__global__ __launch_bounds__(256) void attn_kernel(
    const float* __restrict__ q, const float* __restrict__ k,
    const float* __restrict__ v, const int* __restrict__ tm,
    const int* __restrict__ mask, const float* __restrict__ tiK,
    const float* __restrict__ tiV, float* __restrict__ hh)
{
  int i = blockIdx.x, h = blockIdx.y, b = blockIdx.z;
  int tid = threadIdx.x;
  const int hd = h*WDIM;
  __shared__ float qsh[WDIM];
  __shared__ float sc[SS];
  __shared__ float wred[4];
  __shared__ float part[4][WDIM];
  const int* tmrow = tm + (size_t)(b*SS+i)*SS;

  if (tid < WDIM) qsh[tid] = q[(size_t)(b*SS+i)*DD + hd + tid];
  __syncthreads();

  float score = -1e30f;
  if (tid < SS) {
    int tix = tmrow[tid];
    const float* kr = k   + (size_t)(b*SS+tid)*DD + hd;
    const float* tk = tiK + (size_t)tix*DD + hd;
    float dot = 0.f;
    #pragma unroll
    for (int w = 0; w < WDIM; w += 4) {
      float4 kv = *(const float4*)&kr[w];
      float4 tv = *(const float4*)&tk[w];
      dot += qsh[w+0]*(kv.x+tv.x) + qsh[w+1]*(kv.y+tv.y)
           + qsh[w+2]*(kv.z+tv.z) + qsh[w+3]*(kv.w+tv.w);
    }
    score = dot*0.125f + 10000.0f*(1.0f - (float)mask[b*SS+tid]);
    sc[tid] = score;
  }
  // block max
  float t0 = score;
  #pragma unroll
  for (int off=1; off<64; off<<=1) t0 = fmaxf(t0, __shfl_xor(t0, off));
  if ((tid&63)==0) wred[tid>>6] = t0;
  __syncthreads();
  float mx = fmaxf(fmaxf(wred[0],wred[1]), fmaxf(wred[2],wred[3]));
  __syncthreads();
  float p = 0.f;
  if (tid < SS) { p = expf(sc[tid]-mx); sc[tid] = p; }
  float t1 = p;
  #pragma unroll
  for (int off=1; off<64; off<<=1) t1 += __shfl_xor(t1, off);
  if ((tid&63)==0) wred[tid>>6] = t1;
  __syncthreads();
  float rinv = 1.0f/(wred[0]+wred[1]+wred[2]+wred[3]);

  // output: 4 groups of 64 lanes, each group handles 40 of the 160 j's
  int g = tid >> 6, w = tid & 63;
  float acc = 0.f;
  for (int j = g*40; j < g*40+40; ++j) {
    float a = sc[j];
    int tix = tmrow[j];
    acc += a * (v[(size_t)(b*SS+j)*DD + hd + w] + tiV[(size_t)tix*DD + hd + w]);
  }
  part[g][w] = acc;
  __syncthreads();
  if (tid < WDIM) {
    hh[(size_t)(b*SS+i)*DD + hd + tid] =
      (part[0][tid]+part[1][tid]+part[2][tid]+part[3][tid]) * rinv;
  }
}

// ---------------- launch ----------------
extern "C" void kernel_launch(void* const* d_in, const int* in_sizes, int n_in,
                              void* d_out, int out_size, void* d_ws, size_t ws_size,
                              hipStream_t stream) {
  const int*   x     = (const int*)d_in[0];
  const int*   stamp = (const int*)d_in[1];
  const int*   mask  = (const int*)d_in[2];
  const int*   tm    = (const int*)d_in[3];
  const float* tok   = (const float*)d_in[4];
  const float* month = (const float*)d_in[5];
  const float* day   = (const float*)d_in[6];
  const float* tiK   = (const float*)d_in[7];
  const float* tiV   = (const float*)d_in[8];
  const float* g0    = (const float*)d_in[9];
  const float* b0    = (const float*)d_in[10];
  const float* Wq    = (const float*)d_in[11];
  const float* bq    = (const float*)d_in[12];
  const float* Wk    = (const float*)d_in[13];
  const float* bk    = (const float*)d_in[14];
  const float* Wv    = (const float*)d_in[15];
  const float* bv    = (const float*)d_in[16];
  const float* Wo    = (const float*)d_in[17];
  const float* bo    = (const float*)d_in[18];
  const float* g1    = (const float*)d_in[19];
  const float* b1    = (const float*)d_in[20];
  const float* W1    = (const float*)d_in[21];
  const float* c1    = (const float*)d_in[22];
  const float* W2    = (const float*)d_in[23];
  const float* c2    = (const float*)d_in[24];
  const float* g2    = (const float*)d_in[25];
  const float* b2    = (const float*)d_in[26];

  float* out = (float*)d_out;
  float* ws  = (float*)d_ws;
  const size_t NT = (size_t)MTOK * DD;   // 327,680
  float* h   = ws;
  float* qb  = ws + 1*NT;
  float* kb  = ws + 2*NT;
  float* vb  = ws + 3*NT;
  float* hhb = ws + 4*NT;
  float* tb  = ws + 5*NT;
  float* fb  = ws + 6*NT;                // 640*2048

  embed_ln0_kernel<<<MTOK, 256, 0, stream>>>(x, stamp, tok, month, day, g0, b0, h);

  for (int l = 0; l < 2; ++l) {
    const size_t WDD = (size_t)DD*DD;
    gemm_ep<EPI_NONE><<<dim3(8,10), 256, 0, stream>>>(h, Wq + l*WDD, bq + l*DD, nullptr, qb, MTOK, DD, DD);
    gemm_ep<EPI_NONE><<<dim3(8,10), 256, 0, stream>>>(h, Wk + l*WDD, bk + l*DD, nullptr, kb, MTOK, DD, DD);
    gemm_ep<EPI_NONE><<<dim3(8,10), 256, 0, stream>>>(h, Wv + l*WDD, bv + l*DD, nullptr, vb, MTOK, DD, DD);

    attn_kernel<<<dim3(SS, HH, 4), 256, 0, stream>>>(qb, kb, vb, tm, mask, tiK, tiV, hhb);

    gemm_ep<EPI_RESID><<<dim3(8,10), 256, 0, stream>>>(hhb, Wo + l*WDD, bo + l*DD, h, tb, MTOK, DD, DD);
    ln_kernel<<<MTOK, 256, 0, stream>>>(tb, g1 + l*DD, b1 + l*DD, h);

    gemm_ep<EPI_GELU><<<dim3(32,10), 256, 0, stream>>>(h, W1 + (size_t)l*DD*FFD, c1 + l*FFD, nullptr, fb, MTOK, FFD, DD);
    gemm_ep<EPI_RESID><<<dim3(8,10), 256, 0, stream>>>(fb, W2 + (size_t)l*FFD*DD, c2 + l*DD, h, tb, MTOK, DD, FFD);
    ln_kernel<<<MTOK, 256, 0, stream>>>(tb, g2 + l*DD, b2 + l*DD, (l == 1) ? out : h);
  }
}

// Round 2
// 276.559 us; speedup vs baseline: 2.5279x; 2.5279x over previous
//
#include <hip/hip_runtime.h>
#include <hip/hip_bf16.h>
#include <math.h>

#define SS 160
#define DD 512
#define HH 8
#define WDIM 64
#define MTOK 640
#define FFD 2048

typedef __attribute__((ext_vector_type(8))) short bfrag8;   // 8 bf16 = 4 VGPR
typedef __attribute__((ext_vector_type(4))) float facc4;    // 4 f32 accum
typedef unsigned short u16;

// XOR swizzle of 16B chunks within a 128B row (T2 pattern)
#define SWZ(row, cb) ((cb) ^ (((row)&7) << 4))

// ---------------- weight transpose + fp32->bf16 convert ----------------
// src: [L][K][N] fp32 row-major; dst: per-layer [N][K] bf16 (B^T layout),
// dst += l*dls + rowoff*K  (rowoff lets us pack Wq/Wk/Wv into one [1536][512])
__global__ __launch_bounds__(256) void wconv_t(
    const float* __restrict__ src, __hip_bfloat16* __restrict__ dst,
    int K, int N, int dls, int rowoff)
{
  int l = blockIdx.z;
  src += (size_t)l * K * N;
  dst += (size_t)l * dls + (size_t)rowoff * K;
  __shared__ float tile[64][65];
  int k0 = blockIdx.y * 64, n0 = blockIdx.x * 64;
  int t = threadIdx.x;
  int r = t >> 2, c0 = (t & 3) * 16;
  #pragma unroll
  for (int j = 0; j < 16; j += 4) {
    float4 v4 = *(const float4*)&src[(size_t)(k0 + r) * N + n0 + c0 + j];
    tile[r][c0 + j + 0] = v4.x; tile[r][c0 + j + 1] = v4.y;
    tile[r][c0 + j + 2] = v4.z; tile[r][c0 + j + 3] = v4.w;
  }
  __syncthreads();
  union { u16 u[8]; uint4 v; } pk;
  #pragma unroll
  for (int half = 0; half < 2; ++half) {
    #pragma unroll
    for (int j = 0; j < 8; ++j) {
      __hip_bfloat16 hb = __float2bfloat16(tile[c0 + half * 8 + j][r]);
      pk.u[j] = *reinterpret_cast<u16*>(&hb);
    }
    *(uint4*)&dst[(size_t)(n0 + r) * K + k0 + c0 + half * 8] = pk.v;
  }
}

// ---------------- embedding + LN0 (fp32 + bf16 outputs) ----------------
__global__ __launch_bounds__(256) void embed_ln0_kernel(
    const int* __restrict__ x, const int* __restrict__ stamp,
    const float* __restrict__ tok, const float* __restrict__ month,
    const float* __restrict__ day, const float* __restrict__ g0,
    const float* __restrict__ b0, float* __restrict__ h,
    __hip_bfloat16* __restrict__ hb)
{
  int m = blockIdx.x; int b = m / SS; int s = m % SS; int t = threadIdx.x;
  int tokid = x[m];
  float v0 = tok[tokid*DD + t];
  float v1 = tok[tokid*DD + t + 256];
  if (s > 0) {
    int sidx = (b*(SS-1) + (s-1))*3;
    int mo = stamp[sidx+0], dy = stamp[sidx+1];
    v0 += month[mo*DD+t]     + day[dy*DD+t];
    v1 += month[mo*DD+t+256] + day[dy*DD+t+256];
  }
  float sum = v0+v1, sq = v0*v0+v1*v1;
  #pragma unroll
  for (int off=1; off<64; off<<=1) {
    sum += __shfl_xor(sum, off);
    sq  += __shfl_xor(sq , off);
  }
  __shared__ float ssh[4], qsh[4];
  if ((t&63)==0) { ssh[t>>6]=sum; qsh[t>>6]=sq; }
  __syncthreads();
  float fsum = ssh[0]+ssh[1]+ssh[2]+ssh[3];
  float fsq  = qsh[0]+qsh[1]+qsh[2]+qsh[3];
  float u = fsum * (1.0f/512.0f);
  float var = fsq * (1.0f/512.0f) - u*u;
  float r = rsqrtf(var + 1e-12f);
  float y0 = g0[t]    *((v0-u)*r) + b0[t];
  float y1 = g0[t+256]*((v1-u)*r) + b0[t+256];
  h[m*DD+t]      = y0;  h[m*DD+t+256]  = y1;
  hb[m*DD+t]     = __float2bfloat16(y0);
  hb[m*DD+t+256] = __float2bfloat16(y1);
}

// ---------------- LayerNorm (fp32 out + optional bf16 out) ----------------
__global__ __launch_bounds__(256) void ln_kernel(
    const float* __restrict__ in, const float* __restrict__ g,
    const float* __restrict__ b, float* __restrict__ out,
    __hip_bfloat16* __restrict__ outb)
{
  int m = blockIdx.x; int t = threadIdx.x;
  float v0 = in[m*DD + t];
  float v1 = in[m*DD + t + 256];
  float sum = v0+v1, sq = v0*v0+v1*v1;
  #pragma unroll
  for (int off=1; off<64; off<<=1) {
    sum += __shfl_xor(sum, off);
    sq  += __shfl_xor(sq , off);
  }
  __shared__ float ssh[4], qsh[4];
  if ((t&63)==0) { ssh[t>>6]=sum; qsh[t>>6]=sq; }
  __syncthreads();
  float fsum = ssh[0]+ssh[1]+ssh[2]+ssh[3];
  float fsq  = qsh[0]+qsh[1]+qsh[2]+qsh[3];
  float u = fsum * (1.0f/512.0f);
  float var = fsq * (1.0f/512.0f) - u*u;
  float r = rsqrtf(var + 1e-12f);
  float y0 = g[t]    *((v0-u)*r) + b[t];
  float y1 = g[t+256]*((v1-u)*r) + b[t+256];
  out[m*DD+t]     = y0;
  out[m*DD+t+256] = y1;
  if (outb) {
    outb[m*DD+t]     = __float2bfloat16(y0);
    outb[m*DD+t+256] = __float2bfloat16(y1);
  }
}

// ---------------- MFMA GEMM: C[M,N] = A[M,K](bf16) @ Bt[N,K]^T + bias ----
#define EPI_NONE 0
#define EPI_RESID 1
#define EPI_GELU 2
#define EPI_QKV 3

template<int EPI>
__global__ __launch_bounds__(256) void gemm_mfma(
    const __hip_bfloat16* __restrict__ A,   // [M][K]
    const __hip_bfloat16* __restrict__ Bt,  // [N][K] (transposed weight)
    const float* __restrict__ bias,
    const float* __restrict__ bias2,   // EPI_QKV only
    const float* __restrict__ bias3,   // EPI_QKV only
    const float* __restrict__ resid,   // EPI_RESID only
    float* __restrict__ Cf,
    __hip_bfloat16* __restrict__ Cb,   // EPI_GELU only
    int M, int N, int K)
{
  __shared__ u16 As[64 * 64];
  __shared__ u16 Bs[64 * 64];
  const int tid = threadIdx.x;
  const int m0 = blockIdx.y * 64, n0 = blockIdx.x * 64;

  // staging mapping: thread -> row sr (0..63), 32B chunk at elem sc
  const int sr = tid >> 2, sc = (tid & 3) * 16;
  const char* aPtr = (const char*)(A + (size_t)(m0 + sr) * K + sc);
  const char* bPtr = (const char*)(Bt + (size_t)(n0 + sr) * K + sc);
  const int swz0 = sr * 128 + SWZ(sr, sc * 2);
  const int swz1 = sr * 128 + SWZ(sr, sc * 2 + 16);

  // wave -> 32x32 sub-tile
  const int wid = tid >> 6, lane = tid & 63;
  const int wr = wid >> 1, wc = wid & 1;
  const int fr = lane & 15, fks = lane >> 4;

  facc4 acc[2][2] = {};

  for (int kt = 0; kt < K; kt += 64) {
    uint4 av0 = *(const uint4*)(aPtr + (size_t)kt * 2);
    uint4 av1 = *(const uint4*)(aPtr + (size_t)kt * 2 + 16);
    uint4 bv0 = *(const uint4*)(bPtr + (size_t)kt * 2);
    uint4 bv1 = *(const uint4*)(bPtr + (size_t)kt * 2 + 16);
    __syncthreads();
    *(uint4*)((char*)As + swz0) = av0;
    *(uint4*)((char*)As + swz1) = av1;
    *(uint4*)((char*)Bs + swz0) = bv0;
    *(uint4*)((char*)Bs + swz1) = bv1;
    __syncthreads();

    bfrag8 af[2][2], bfr[2][2];
    #pragma unroll
    for (int ks = 0; ks < 2; ++ks) {
      #pragma unroll
      for (int mf = 0; mf < 2; ++mf) {
        int rA = wr * 32 + mf * 16 + fr;
        af[ks][mf] = *(const bfrag8*)((const char*)As + rA * 128 + SWZ(rA, 64 * ks + 16 * fks));
      }
      #pragma unroll
      for (int nf = 0; nf < 2; ++nf) {
        int rB = wc * 32 + nf * 16 + fr;
        bfr[ks][nf] = *(const bfrag8*)((const char*)Bs + rB * 128 + SWZ(rB, 64 * ks + 16 * fks));
      }
    }
    #pragma unroll
    for (int ks = 0; ks < 2; ++ks)
      #pragma unroll
      for (int mf = 0; mf < 2; ++mf)
        #pragma unroll
        for (int nf = 0; nf < 2; ++nf)
          acc[mf][nf] = __builtin_amdgcn_mfma_f32_16x16x32_bf16(
              af[ks][mf], bfr[ks][nf], acc[mf][nf], 0, 0, 0);
  }

  // epilogue: D[row=4*fks+j][col=fr] per fragment
  #pragma unroll
  for (int mf = 0; mf < 2; ++mf) {
    #pragma unroll
    for (int nf = 0; nf < 2; ++nf) {
      int col = n0 + wc * 32 + nf * 16 + fr;
      float bb;
      if (EPI == EPI_QKV)
        bb = col < 512 ? bias[col] : (col < 1024 ? bias2[col - 512] : bias3[col - 1024]);
      else
        bb = bias[col];
      #pragma unroll
      for (int j = 0; j < 4; ++j) {
        int row = m0 + wr * 32 + mf * 16 + fks * 4 + j;
        float c = acc[mf][nf][j] + bb;
        if (EPI == EPI_RESID) c += resid[(size_t)row * N + col];
        if (EPI == EPI_GELU) {
          c = 0.5f * c * (1.0f + erff(c * 0.70710678118654752f));
          Cb[(size_t)row * N + col] = __float2bfloat16(c);
        } else {
          Cf[(size_t)row * N + col] = c;
        }
      }
    }
  }
}

// ---------------- fused attention (one block per (i,h,b)) ----------------
// q/k/v packed in qkv[M][1536] at offsets 0/512/1024
__global__ __launch_bounds__(256) void attn_kernel(
    const float* __restrict__ qkv, const int* __restrict__ tm,
    const int* __restrict__ mask, const float* __restrict__ tiK,
    const float* __restrict__ tiV, __hip_bfloat16* __restrict__ hh)
{
  int i = blockIdx.x, h = blockIdx.y, b = blockIdx.z;
  int tid = threadIdx.x;
  const int hd = h*WDIM;
  __shared__ float qsh[WDIM];
  __shared__ float sc[SS];
  __shared__ float wred[4];
  __shared__ float part[4][WDIM];
  const int* tmrow = tm + (size_t)(b*SS+i)*SS;

  if (tid < WDIM) qsh[tid] = qkv[(size_t)(b*SS+i)*1536 + hd + tid];
  __syncthreads();

  float score = -1e30f;
  if (tid < SS) {
    int tix = tmrow[tid];
    const float* kr = qkv + (size_t)(b*SS+tid)*1536 + 512 + hd;
    const float* tk = tiK + (size_t)tix*DD + hd;
    float dot = 0.f;
    #pragma unroll
    for (int w = 0; w < WDIM; w += 4) {
      float4 kv = *(const float4*)&kr[w];
      float4 tv = *(const float4*)&tk[w];
      dot += qsh[w+0]*(kv.x+tv.x) + qsh[w+1]*(kv.y+tv.y)
           + qsh[w+2]*(kv.z+tv.z) + qsh[w+3]*(kv.w+tv.w);
    }
    score = dot*0.125f + 10000.0f*(1.0f - (float)mask[b*SS+tid]);
    sc[tid] = score;
  }
  float t0 = score;
  #pragma unroll
  for (int off=1; off<64; off<<=1) t0 = fmaxf(t0, __shfl_xor(t0, off));
  if ((tid&63)==0) wred[tid>>6] = t0;
  __syncthreads();
  float mx = fmaxf(fmaxf(wred[0],wred[1]), fmaxf(wred[2],wred[3]));
  __syncthreads();
  float p = 0.f;
  if (tid < SS) { p = expf(sc[tid]-mx); sc[tid] = p; }
  float t1 = p;
  #pragma unroll
  for (int off=1; off<64; off<<=1) t1 += __shfl_xor(t1, off);
  if ((tid&63)==0) wred[tid>>6] = t1;
  __syncthreads();
  float rinv = 1.0f/(wred[0]+wred[1]+wred[2]+wred[3]);

  int g = tid >> 6, w = tid & 63;
  float acc = 0.f;
  for (int j = g*40; j < g*40+40; ++j) {
    float a = sc[j];
    int tix = tmrow[j];
    acc += a * (qkv[(size_t)(b*SS+j)*1536 + 1024 + hd + w] + tiV[(size_t)tix*DD + hd + w]);
  }
  part[g][w] = acc;
  __syncthreads();
  if (tid < WDIM) {
    hh[(size_t)(b*SS+i)*DD + hd + tid] =
      __float2bfloat16((part[0][tid]+part[1][tid]+part[2][tid]+part[3][tid]) * rinv);
  }
}

// ---------------- launch ----------------
extern "C" void kernel_launch(void* const* d_in, const int* in_sizes, int n_in,
                              void* d_out, int out_size, void* d_ws, size_t ws_size,
                              hipStream_t stream) {
  const int*   x     = (const int*)d_in[0];
  const int*   stamp = (const int*)d_in[1];
  const int*   mask  = (const int*)d_in[2];
  const int*   tm    = (const int*)d_in[3];
  const float* tok   = (const float*)d_in[4];
  const float* month = (const float*)d_in[5];
  const float* day   = (const float*)d_in[6];
  const float* tiK   = (const float*)d_in[7];
  const float* tiV   = (const float*)d_in[8];
  const float* g0    = (const float*)d_in[9];
  const float* b0    = (const float*)d_in[10];
  const float* Wq    = (const float*)d_in[11];
  const float* bq    = (const float*)d_in[12];
  const float* Wk    = (const float*)d_in[13];
  const float* bk    = (const float*)d_in[14];
  const float* Wv    = (const float*)d_in[15];
  const float* bv    = (const float*)d_in[16];
  const float* Wo    = (const float*)d_in[17];
  const float* bo    = (const float*)d_in[18];
  const float* g1    = (const float*)d_in[19];
  const float* b1    = (const float*)d_in[20];
  const float* W1    = (const float*)d_in[21];
  const float* c1    = (const float*)d_in[22];
  const float* W2    = (const float*)d_in[23];
  const float* c2    = (const float*)d_in[24];
  const float* g2    = (const float*)d_in[25];
  const float* b2    = (const float*)d_in[26];

  float* out = (float*)d_out;
  const size_t NT = (size_t)MTOK * DD;   // 327,680

  char* p = (char*)d_ws;
  float* h    = (float*)p;  p += NT * 4;
  float* qkvb = (float*)p;  p += (size_t)MTOK * 1536 * 4;
  float* tb   = (float*)p;  p += NT * 4;
  __hip_bfloat16* h_bf  = (__hip_bfloat16*)p;  p += NT * 2;
  __hip_bfloat16* hh_bf = (__hip_bfloat16*)p;  p += NT * 2;
  __hip_bfloat16* fb_bf = (__hip_bfloat16*)p;  p += (size_t)MTOK * FFD * 2;
  __hip_bfloat16* wqkv  = (__hip_bfloat16*)p;  p += (size_t)2 * 1536 * 512 * 2;
  __hip_bfloat16* wo_t  = (__hip_bfloat16*)p;  p += (size_t)2 * 512 * 512 * 2;
  __hip_bfloat16* w1_t  = (__hip_bfloat16*)p;  p += (size_t)2 * 2048 * 512 * 2;
  __hip_bfloat16* w2_t  = (__hip_bfloat16*)p;  p += (size_t)2 * 512 * 2048 * 2;

  // weight convert+transpose (per call; deterministic)
  wconv_t<<<dim3(8, 8, 2), 256, 0, stream>>>(Wq, wqkv, 512, 512, 1536*512, 0);
  wconv_t<<<dim3(8, 8, 2), 256, 0, stream>>>(Wk, wqkv, 512, 512, 1536*512, 512);
  wconv_t<<<dim3(8, 8, 2), 256, 0, stream>>>(Wv, wqkv, 512, 512, 1536*512, 1024);
  wconv_t<<<dim3(8, 8, 2), 256, 0, stream>>>(Wo, wo_t, 512, 512, 512*512, 0);
  wconv_t<<<dim3(32, 8, 2), 256, 0, stream>>>(W1, w1_t, 512, 2048, 2048*512, 0);
  wconv_t<<<dim3(8, 32, 2), 256, 0, stream>>>(W2, w2_t, 2048, 512, 512*2048, 0);

  embed_ln0_kernel<<<MTOK, 256, 0, stream>>>(x, stamp, tok, month, day, g0, b0, h, h_bf);

  for (int l = 0; l < 2; ++l) {
    gemm_mfma<EPI_QKV><<<dim3(24, 10), 256, 0, stream>>>(
        h_bf, wqkv + (size_t)l * 1536 * 512, bq + l*DD, bk + l*DD, bv + l*DD,
        nullptr, qkvb, nullptr, MTOK, 1536, 512);

    attn_kernel<<<dim3(SS, HH, 4), 256, 0, stream>>>(qkvb, tm, mask, tiK, tiV, hh_bf);

    gemm_mfma<EPI_RESID><<<dim3(8, 10), 256, 0, stream>>>(
        hh_bf, wo_t + (size_t)l * 512 * 512, bo + l*DD, nullptr, nullptr,
        h, tb, nullptr, MTOK, 512, 512);
    ln_kernel<<<MTOK, 256, 0, stream>>>(tb, g1 + l*DD, b1 + l*DD, h, h_bf);

    gemm_mfma<EPI_GELU><<<dim3(32, 10), 256, 0, stream>>>(
        h_bf, w1_t + (size_t)l * 2048 * 512, c1 + l*FFD, nullptr, nullptr,
        nullptr, nullptr, fb_bf, MTOK, FFD, 512);

    gemm_mfma<EPI_RESID><<<dim3(8, 10), 256, 0, stream>>>(
        fb_bf, w2_t + (size_t)l * 512 * 2048, c2 + l*DD, nullptr, nullptr,
        h, tb, nullptr, MTOK, 512, 2048);
    ln_kernel<<<MTOK, 256, 0, stream>>>(tb, g2 + l*DD, b2 + l*DD,
                                        (l == 1) ? out : h,
                                        (l == 1) ? nullptr : h_bf);
  }
}

// Round 3
// 189.323 us; speedup vs baseline: 3.6926x; 1.4608x over previous
//
#include <hip/hip_runtime.h>
#include <hip/hip_bf16.h>
#include <math.h>

#define SS 160
#define DD 512
#define HH 8
#define WDIM 64
#define MTOK 640
#define FFD 2048
#define NTT 257   // T+1 time-embedding rows

typedef __attribute__((ext_vector_type(8))) short bfrag8;   // 8 bf16 = 4 VGPR
typedef __attribute__((ext_vector_type(4))) float facc4;    // 4 f32 accum
typedef unsigned short u16;

// XOR swizzle of 16B chunks within a 128B row (T2 pattern)
#define SWZ(row, cb) ((cb) ^ (((row)&7) << 4))

// ---------------- weight transpose + fp32->bf16 convert ----------------
__global__ __launch_bounds__(256) void wconv_t(
    const float* __restrict__ src, __hip_bfloat16* __restrict__ dst,
    int K, int N, int dls, int rowoff)
{
  int l = blockIdx.z;
  src += (size_t)l * K * N;
  dst += (size_t)l * dls + (size_t)rowoff * K;
  __shared__ float tile[64][65];
  int k0 = blockIdx.y * 64, n0 = blockIdx.x * 64;
  int t = threadIdx.x;
  int r = t >> 2, c0 = (t & 3) * 16;
  #pragma unroll
  for (int j = 0; j < 16; j += 4) {
    float4 v4 = *(const float4*)&src[(size_t)(k0 + r) * N + n0 + c0 + j];
    tile[r][c0 + j + 0] = v4.x; tile[r][c0 + j + 1] = v4.y;
    tile[r][c0 + j + 2] = v4.z; tile[r][c0 + j + 3] = v4.w;
  }
  __syncthreads();
  union { u16 u[8]; uint4 v; } pk;
  #pragma unroll
  for (int half = 0; half < 2; ++half) {
    #pragma unroll
    for (int j = 0; j < 8; ++j) {
      __hip_bfloat16 hb = __float2bfloat16(tile[c0 + half * 8 + j][r]);
      pk.u[j] = *reinterpret_cast<u16*>(&hb);
    }
    *(uint4*)&dst[(size_t)(n0 + r) * K + k0 + c0 + half * 8] = pk.v;
  }
}

// ---------------- generic fp32 -> bf16 convert (vector x4) ----------------
__global__ __launch_bounds__(256) void conv_bf16(
    const float* __restrict__ src, __hip_bfloat16* __restrict__ dst, int n4)
{
  int i = blockIdx.x * 256 + threadIdx.x;
  if (i < n4) {
    float4 v = *(const float4*)(src + (size_t)i * 4);
    union { u16 u[4]; uint2 w; } pk;
    __hip_bfloat16 h0 = __float2bfloat16(v.x), h1 = __float2bfloat16(v.y);
    __hip_bfloat16 h2 = __float2bfloat16(v.z), h3 = __float2bfloat16(v.w);
    pk.u[0] = *(u16*)&h0; pk.u[1] = *(u16*)&h1;
    pk.u[2] = *(u16*)&h2; pk.u[3] = *(u16*)&h3;
    *(uint2*)(dst + (size_t)i * 4) = pk.w;
  }
}

// ---------------- embedding + LN0 ----------------
__global__ __launch_bounds__(256) void embed_ln0_kernel(
    const int* __restrict__ x, const int* __restrict__ stamp,
    const float* __restrict__ tok, const float* __restrict__ month,
    const float* __restrict__ day, const float* __restrict__ g0,
    const float* __restrict__ b0, float* __restrict__ h,
    __hip_bfloat16* __restrict__ hb)
{
  int m = blockIdx.x; int b = m / SS; int s = m % SS; int t = threadIdx.x;
  int tokid = x[m];
  float v0 = tok[tokid*DD + t];
  float v1 = tok[tokid*DD + t + 256];
  if (s > 0) {
    int sidx = (b*(SS-1) + (s-1))*3;
    int mo = stamp[sidx+0], dy = stamp[sidx+1];
    v0 += month[mo*DD+t]     + day[dy*DD+t];
    v1 += month[mo*DD+t+256] + day[dy*DD+t+256];
  }
  float sum = v0+v1, sq = v0*v0+v1*v1;
  #pragma unroll
  for (int off=1; off<64; off<<=1) {
    sum += __shfl_xor(sum, off);
    sq  += __shfl_xor(sq , off);
  }
  __shared__ float ssh[4], qsh[4];
  if ((t&63)==0) { ssh[t>>6]=sum; qsh[t>>6]=sq; }
  __syncthreads();
  float fsum = ssh[0]+ssh[1]+ssh[2]+ssh[3];
  float fsq  = qsh[0]+qsh[1]+qsh[2]+qsh[3];
  float u = fsum * (1.0f/512.0f);
  float var = fsq * (1.0f/512.0f) - u*u;
  float r = rsqrtf(var + 1e-12f);
  float y0 = g0[t]    *((v0-u)*r) + b0[t];
  float y1 = g0[t+256]*((v1-u)*r) + b0[t+256];
  h[m*DD+t]      = y0;  h[m*DD+t+256]  = y1;
  hb[m*DD+t]     = __float2bfloat16(y0);
  hb[m*DD+t+256] = __float2bfloat16(y1);
}

// ---------------- LayerNorm ----------------
__global__ __launch_bounds__(256) void ln_kernel(
    const float* __restrict__ in, const float* __restrict__ g,
    const float* __restrict__ b, float* __restrict__ out,
    __hip_bfloat16* __restrict__ outb)
{
  int m = blockIdx.x; int t = threadIdx.x;
  float v0 = in[m*DD + t];
  float v1 = in[m*DD + t + 256];
  float sum = v0+v1, sq = v0*v0+v1*v1;
  #pragma unroll
  for (int off=1; off<64; off<<=1) {
    sum += __shfl_xor(sum, off);
    sq  += __shfl_xor(sq , off);
  }
  __shared__ float ssh[4], qsh[4];
  if ((t&63)==0) { ssh[t>>6]=sum; qsh[t>>6]=sq; }
  __syncthreads();
  float fsum = ssh[0]+ssh[1]+ssh[2]+ssh[3];
  float fsq  = qsh[0]+qsh[1]+qsh[2]+qsh[3];
  float u = fsum * (1.0f/512.0f);
  float var = fsq * (1.0f/512.0f) - u*u;
  float r = rsqrtf(var + 1e-12f);
  float y0 = g[t]    *((v0-u)*r) + b[t];
  float y1 = g[t+256]*((v1-u)*r) + b[t+256];
  out[m*DD+t]     = y0;
  out[m*DD+t+256] = y1;
  if (outb) {
    outb[m*DD+t]     = __float2bfloat16(y0);
    outb[m*DD+t+256] = __float2bfloat16(y1);
  }
}

// ---------------- MFMA GEMM: C[M,N] = A[M,K](bf16) @ Bt[N,K]^T + bias ----
#define EPI_RESID 1
#define EPI_GELU 2
#define EPI_QKV 3

template<int EPI>
__global__ __launch_bounds__(256) void gemm_mfma(
    const __hip_bfloat16* __restrict__ A,   // [M][K]
    const __hip_bfloat16* __restrict__ Bt,  // [N][K]
    const float* __restrict__ bias,
    const float* __restrict__ bias2,   // EPI_QKV only
    const float* __restrict__ bias3,   // EPI_QKV only
    const float* __restrict__ resid,   // EPI_RESID only
    float* __restrict__ Cf,
    __hip_bfloat16* __restrict__ Cb,   // EPI_GELU / EPI_QKV
    int M, int N, int K)
{
  __shared__ u16 As[64 * 64];
  __shared__ u16 Bs[64 * 64];
  const int tid = threadIdx.x;
  const int m0 = blockIdx.y * 64, n0 = blockIdx.x * 64;

  const int sr = tid >> 2, sc = (tid & 3) * 16;
  const char* aPtr = (const char*)(A + (size_t)(m0 + sr) * K + sc);
  const char* bPtr = (const char*)(Bt + (size_t)(n0 + sr) * K + sc);
  const int swz0 = sr * 128 + SWZ(sr, sc * 2);
  const int swz1 = sr * 128 + SWZ(sr, sc * 2 + 16);

  const int wid = tid >> 6, lane = tid & 63;
  const int wr = wid >> 1, wc = wid & 1;
  const int fr = lane & 15, fks = lane >> 4;

  facc4 acc[2][2] = {};

  for (int kt = 0; kt < K; kt += 64) {
    uint4 av0 = *(const uint4*)(aPtr + (size_t)kt * 2);
    uint4 av1 = *(const uint4*)(aPtr + (size_t)kt * 2 + 16);
    uint4 bv0 = *(const uint4*)(bPtr + (size_t)kt * 2);
    uint4 bv1 = *(const uint4*)(bPtr + (size_t)kt * 2 + 16);
    __syncthreads();
    *(uint4*)((char*)As + swz0) = av0;
    *(uint4*)((char*)As + swz1) = av1;
    *(uint4*)((char*)Bs + swz0) = bv0;
    *(uint4*)((char*)Bs + swz1) = bv1;
    __syncthreads();

    bfrag8 af[2][2], bfr[2][2];
    #pragma unroll
    for (int ks = 0; ks < 2; ++ks) {
      #pragma unroll
      for (int mf = 0; mf < 2; ++mf) {
        int rA = wr * 32 + mf * 16 + fr;
        af[ks][mf] = *(const bfrag8*)((const char*)As + rA * 128 + SWZ(rA, 64 * ks + 16 * fks));
      }
      #pragma unroll
      for (int nf = 0; nf < 2; ++nf) {
        int rB = wc * 32 + nf * 16 + fr;
        bfr[ks][nf] = *(const bfrag8*)((const char*)Bs + rB * 128 + SWZ(rB, 64 * ks + 16 * fks));
      }
    }
    #pragma unroll
    for (int ks = 0; ks < 2; ++ks)
      #pragma unroll
      for (int mf = 0; mf < 2; ++mf)
        #pragma unroll
        for (int nf = 0; nf < 2; ++nf)
          acc[mf][nf] = __builtin_amdgcn_mfma_f32_16x16x32_bf16(
              af[ks][mf], bfr[ks][nf], acc[mf][nf], 0, 0, 0);
  }

  #pragma unroll
  for (int mf = 0; mf < 2; ++mf) {
    #pragma unroll
    for (int nf = 0; nf < 2; ++nf) {
      int col = n0 + wc * 32 + nf * 16 + fr;
      float bb;
      if (EPI == EPI_QKV)
        bb = col < 512 ? bias[col] : (col < 1024 ? bias2[col - 512] : bias3[col - 1024]);
      else
        bb = bias[col];
      #pragma unroll
      for (int j = 0; j < 4; ++j) {
        int row = m0 + wr * 32 + mf * 16 + fks * 4 + j;
        float c = acc[mf][nf][j] + bb;
        if (EPI == EPI_RESID) {
          c += resid[(size_t)row * N + col];
          Cf[(size_t)row * N + col] = c;
        } else {
          if (EPI == EPI_GELU) c = 0.5f * c * (1.0f + erff(c * 0.70710678118654752f));
          Cb[(size_t)row * N + col] = __float2bfloat16(c);
        }
      }
    }
  }
}

// ---------------- Sk = Q @ K^T per (b,h): [160x64]@[64x160] ----------------
__global__ __launch_bounds__(256) void gemm_sk(
    const __hip_bfloat16* __restrict__ qkv, float* __restrict__ Sk)
{
  const int z = blockIdx.z, b = z >> 3, h = z & 7;
  const __hip_bfloat16* A  = qkv + (size_t)b * SS * 1536 + h * 64;        // q rows
  const __hip_bfloat16* Bt = qkv + (size_t)b * SS * 1536 + 512 + h * 64;  // k rows
  float* C = Sk + (size_t)z * SS * SS;
  __shared__ u16 As[64 * 64];
  __shared__ u16 Bs[64 * 64];
  const int tid = threadIdx.x;
  const int m0 = blockIdx.y * 64, n0 = blockIdx.x * 64;
  const int sr = tid >> 2, sc = (tid & 3) * 16;
  const int ar = min(m0 + sr, SS - 1), br = min(n0 + sr, SS - 1);
  uint4 av0 = *(const uint4*)(A + (size_t)ar * 1536 + sc);
  uint4 av1 = *(const uint4*)(A + (size_t)ar * 1536 + sc + 8);
  uint4 bv0 = *(const uint4*)(Bt + (size_t)br * 1536 + sc);
  uint4 bv1 = *(const uint4*)(Bt + (size_t)br * 1536 + sc + 8);
  const int swz0 = sr * 128 + SWZ(sr, sc * 2);
  const int swz1 = sr * 128 + SWZ(sr, sc * 2 + 16);
  *(uint4*)((char*)As + swz0) = av0;
  *(uint4*)((char*)As + swz1) = av1;
  *(uint4*)((char*)Bs + swz0) = bv0;
  *(uint4*)((char*)Bs + swz1) = bv1;
  __syncthreads();

  const int wid = tid >> 6, lane = tid & 63;
  const int wr = wid >> 1, wc = wid & 1;
  const int fr = lane & 15, fks = lane >> 4;
  facc4 acc[2][2] = {};
  bfrag8 af[2][2], bfr[2][2];
  #pragma unroll
  for (int ks = 0; ks < 2; ++ks) {
    #pragma unroll
    for (int mf = 0; mf < 2; ++mf) {
      int rA = wr * 32 + mf * 16 + fr;
      af[ks][mf] = *(const bfrag8*)((const char*)As + rA * 128 + SWZ(rA, 64 * ks + 16 * fks));
    }
    #pragma unroll
    for (int nf = 0; nf < 2; ++nf) {
      int rB = wc * 32 + nf * 16 + fr;
      bfr[ks][nf] = *(const bfrag8*)((const char*)Bs + rB * 128 + SWZ(rB, 64 * ks + 16 * fks));
    }
  }
  #pragma unroll
  for (int ks = 0; ks < 2; ++ks)
    #pragma unroll
    for (int mf = 0; mf < 2; ++mf)
      #pragma unroll
      for (int nf = 0; nf < 2; ++nf)
        acc[mf][nf] = __builtin_amdgcn_mfma_f32_16x16x32_bf16(
            af[ks][mf], bfr[ks][nf], acc[mf][nf], 0, 0, 0);

  #pragma unroll
  for (int mf = 0; mf < 2; ++mf)
    #pragma unroll
    for (int nf = 0; nf < 2; ++nf) {
      int col = n0 + wc * 32 + nf * 16 + fr;
      #pragma unroll
      for (int j = 0; j < 4; ++j) {
        int row = m0 + wr * 32 + mf * 16 + fks * 4 + j;
        if (row < SS && col < SS) C[row * SS + col] = acc[mf][nf][j];
      }
    }
}

// ---------------- G[h][m][t] = q_m . tiK_t  (per head GEMM) ----------------
__global__ __launch_bounds__(256) void gemm_g(
    const __hip_bfloat16* __restrict__ qkv,
    const __hip_bfloat16* __restrict__ tikb, float* __restrict__ G)
{
  const int h = blockIdx.z;
  const __hip_bfloat16* A  = qkv + h * 64;    // [640][1536] q slice
  const __hip_bfloat16* Bt = tikb + h * 64;   // [257][512]
  __shared__ u16 As[64 * 64];
  __shared__ u16 Bs[64 * 64];
  const int tid = threadIdx.x;
  const int m0 = blockIdx.y * 64, n0 = blockIdx.x * 64;
  const int sr = tid >> 2, sc = (tid & 3) * 16;
  const int br = min(n0 + sr, NTT - 1);
  uint4 av0 = *(const uint4*)(A + (size_t)(m0 + sr) * 1536 + sc);
  uint4 av1 = *(const uint4*)(A + (size_t)(m0 + sr) * 1536 + sc + 8);
  uint4 bv0 = *(const uint4*)(Bt + (size_t)br * 512 + sc);
  uint4 bv1 = *(const uint4*)(Bt + (size_t)br * 512 + sc + 8);
  const int swz0 = sr * 128 + SWZ(sr, sc * 2);
  const int swz1 = sr * 128 + SWZ(sr, sc * 2 + 16);
  *(uint4*)((char*)As + swz0) = av0;
  *(uint4*)((char*)As + swz1) = av1;
  *(uint4*)((char*)Bs + swz0) = bv0;
  *(uint4*)((char*)Bs + swz1) = bv1;
  __syncthreads();

  const int wid = tid >> 6, lane = tid & 63;
  const int wr = wid >> 1, wc = wid & 1;
  const int fr = lane & 15, fks = lane >> 4;
  facc4 acc[2][2] = {};
  bfrag8 af[2][2], bfr[2][2];
  #pragma unroll
  for (int ks = 0; ks < 2; ++ks) {
    #pragma unroll
    for (int mf = 0; mf < 2; ++mf) {
      int rA = wr * 32 + mf * 16 + fr;
      af[ks][mf] = *(const bfrag8*)((const char*)As + rA * 128 + SWZ(rA, 64 * ks + 16 * fks));
    }
    #pragma unroll
    for (int nf = 0; nf < 2; ++nf) {
      int rB = wc * 32 + nf * 16 + fr;
      bfr[ks][nf] = *(const bfrag8*)((const char*)Bs + rB * 128 + SWZ(rB, 64 * ks + 16 * fks));
    }
  }
  #pragma unroll
  for (int ks = 0; ks < 2; ++ks)
    #pragma unroll
    for (int mf = 0; mf < 2; ++mf)
      #pragma unroll
      for (int nf = 0; nf < 2; ++nf)
        acc[mf][nf] = __builtin_amdgcn_mfma_f32_16x16x32_bf16(
            af[ks][mf], bfr[ks][nf], acc[mf][nf], 0, 0, 0);

  #pragma unroll
  for (int mf = 0; mf < 2; ++mf)
    #pragma unroll
    for (int nf = 0; nf < 2; ++nf) {
      int col = n0 + wc * 32 + nf * 16 + fr;
      #pragma unroll
      for (int j = 0; j < 4; ++j) {
        int row = m0 + wr * 32 + mf * 16 + fks * 4 + j;
        if (col < NTT)
          G[((size_t)h * MTOK + row) * NTT + col] = acc[mf][nf][j];
      }
    }
}

// ---------------- attention: softmax + PV (scores precomputed) ------------
// grid (20, 8, 4): 8 queries per block, wave = 2 queries, lanes = w-dim
__global__ __launch_bounds__(256) void attn2(
    const __hip_bfloat16* __restrict__ qkv,
    const float* __restrict__ Sk, const float* __restrict__ G,
    const int* __restrict__ tm, const int* __restrict__ mask,
    const float* __restrict__ tiV, __hip_bfloat16* __restrict__ hh)
{
  const int h = blockIdx.y, b = blockIdx.z;
  const int ib0 = blockIdx.x * 8;
  const int tid = threadIdx.x, wv = tid >> 6, lane = tid & 63;
  __shared__ float P[8][176];
  __shared__ int tmsh[8][176];

  float rinvs[2];
  #pragma unroll
  for (int rr = 0; rr < 2; ++rr) {
    const int r = wv * 2 + rr, i = ib0 + r, m = b * SS + i;
    const float* Grow = G + ((size_t)h * MTOK + m) * NTT;
    const float* Srow = Sk + ((size_t)(b * 8 + h) * SS + i) * SS;
    const int* tmrow = tm + (size_t)m * SS;
    float sv[3];
    float mx = -1e30f;
    #pragma unroll
    for (int g = 0; g < 3; ++g) {
      int j = lane + g * 64;
      if (j < SS) {
        int t = tmrow[j];
        tmsh[r][j] = t;
        float s = (Srow[j] + Grow[t]) * 0.125f
                + 10000.0f * (1.0f - (float)mask[b * SS + j]);
        sv[g] = s; mx = fmaxf(mx, s);
      } else sv[g] = -1e30f;
    }
    #pragma unroll
    for (int off = 1; off < 64; off <<= 1) mx = fmaxf(mx, __shfl_xor(mx, off));
    float sum = 0.f;
    #pragma unroll
    for (int g = 0; g < 3; ++g) {
      int j = lane + g * 64;
      if (j < SS) { float p = expf(sv[g] - mx); P[r][j] = p; sum += p; }
    }
    #pragma unroll
    for (int off = 1; off < 64; off <<= 1) sum += __shfl_xor(sum, off);
    rinvs[rr] = 1.0f / sum;
  }

  // phase 2: same wave's rows only -> no barrier needed
  const int r0 = wv * 2, r1 = r0 + 1;
  const int i0 = ib0 + r0, i1 = ib0 + r1;
  const __hip_bfloat16* vbase = qkv + (size_t)b * SS * 1536 + 1024 + h * 64 + lane;
  const float* tvbase = tiV + h * 64 + lane;
  float acc0 = 0.f, acc1 = 0.f;
  #pragma unroll 4
  for (int j = 0; j < SS; ++j) {
    float vv = __bfloat162float(vbase[(size_t)j * 1536]);
    float a0 = P[r0][j], a1 = P[r1][j];
    int t0 = tmsh[r0][j], t1 = tmsh[r1][j];
    acc0 += a0 * (vv + tvbase[(size_t)t0 * 512]);
    acc1 += a1 * (vv + tvbase[(size_t)t1 * 512]);
  }
  hh[((size_t)(b * SS) + i0) * DD + h * 64 + lane] = __float2bfloat16(acc0 * rinvs[0]);
  hh[((size_t)(b * SS) + i1) * DD + h * 64 + lane] = __float2bfloat16(acc1 * rinvs[1]);
}

// ---------------- launch ----------------
extern "C" void kernel_launch(void* const* d_in, const int* in_sizes, int n_in,
                              void* d_out, int out_size, void* d_ws, size_t ws_size,
                              hipStream_t stream) {
  const int*   x     = (const int*)d_in[0];
  const int*   stamp = (const int*)d_in[1];
  const int*   mask  = (const int*)d_in[2];
  const int*   tm    = (const int*)d_in[3];
  const float* tok   = (const float*)d_in[4];
  const float* month = (const float*)d_in[5];
  const float* day   = (const float*)d_in[6];
  const float* tiK   = (const float*)d_in[7];
  const float* tiV   = (const float*)d_in[8];
  const float* g0    = (const float*)d_in[9];
  const float* b0    = (const float*)d_in[10];
  const float* Wq    = (const float*)d_in[11];
  const float* bq    = (const float*)d_in[12];
  const float* Wk    = (const float*)d_in[13];
  const float* bk    = (const float*)d_in[14];
  const float* Wv    = (const float*)d_in[15];
  const float* bv    = (const float*)d_in[16];
  const float* Wo    = (const float*)d_in[17];
  const float* bo    = (const float*)d_in[18];
  const float* g1    = (const float*)d_in[19];
  const float* b1    = (const float*)d_in[20];
  const float* W1    = (const float*)d_in[21];
  const float* c1    = (const float*)d_in[22];
  const float* W2    = (const float*)d_in[23];
  const float* c2    = (const float*)d_in[24];
  const float* g2    = (const float*)d_in[25];
  const float* b2    = (const float*)d_in[26];

  float* out = (float*)d_out;
  const size_t NT = (size_t)MTOK * DD;

  char* p = (char*)d_ws;
  float* h    = (float*)p;  p += NT * 4;
  float* tb   = (float*)p;  p += NT * 4;
  float* Skb  = (float*)p;  p += (size_t)32 * SS * SS * 4;        // 3.28 MB
  float* Gb   = (float*)p;  p += (size_t)HH * MTOK * NTT * 4;     // 5.27 MB
  __hip_bfloat16* h_bf   = (__hip_bfloat16*)p;  p += NT * 2;
  __hip_bfloat16* hh_bf  = (__hip_bfloat16*)p;  p += NT * 2;
  __hip_bfloat16* fb_bf  = (__hip_bfloat16*)p;  p += (size_t)MTOK * FFD * 2;
  __hip_bfloat16* qkv_bf = (__hip_bfloat16*)p;  p += (size_t)MTOK * 1536 * 2;
  __hip_bfloat16* tikb   = (__hip_bfloat16*)p;  p += (size_t)NTT * DD * 2;
  __hip_bfloat16* wqkv   = (__hip_bfloat16*)p;  p += (size_t)2 * 1536 * 512 * 2;
  __hip_bfloat16* wo_t   = (__hip_bfloat16*)p;  p += (size_t)2 * 512 * 512 * 2;
  __hip_bfloat16* w1_t   = (__hip_bfloat16*)p;  p += (size_t)2 * 2048 * 512 * 2;
  __hip_bfloat16* w2_t   = (__hip_bfloat16*)p;  p += (size_t)2 * 512 * 2048 * 2;

  wconv_t<<<dim3(8, 8, 2), 256, 0, stream>>>(Wq, wqkv, 512, 512, 1536*512, 0);
  wconv_t<<<dim3(8, 8, 2), 256, 0, stream>>>(Wk, wqkv, 512, 512, 1536*512, 512);
  wconv_t<<<dim3(8, 8, 2), 256, 0, stream>>>(Wv, wqkv, 512, 512, 1536*512, 1024);
  wconv_t<<<dim3(8, 8, 2), 256, 0, stream>>>(Wo, wo_t, 512, 512, 512*512, 0);
  wconv_t<<<dim3(32, 8, 2), 256, 0, stream>>>(W1, w1_t, 512, 2048, 2048*512, 0);
  wconv_t<<<dim3(8, 32, 2), 256, 0, stream>>>(W2, w2_t, 2048, 512, 512*2048, 0);
  conv_bf16<<<(NTT * DD / 4 + 255) / 256, 256, 0, stream>>>(tiK, tikb, NTT * DD / 4);

  embed_ln0_kernel<<<MTOK, 256, 0, stream>>>(x, stamp, tok, month, day, g0, b0, h, h_bf);

  for (int l = 0; l < 2; ++l) {
    gemm_mfma<EPI_QKV><<<dim3(24, 10), 256, 0, stream>>>(
        h_bf, wqkv + (size_t)l * 1536 * 512, bq + l*DD, bk + l*DD, bv + l*DD,
        nullptr, nullptr, qkv_bf, MTOK, 1536, 512);

    gemm_sk<<<dim3(3, 3, 32), 256, 0, stream>>>(qkv_bf, Skb);
    gemm_g<<<dim3(5, 10, 8), 256, 0, stream>>>(qkv_bf, tikb, Gb);

    attn2<<<dim3(20, 8, 4), 256, 0, stream>>>(qkv_bf, Skb, Gb, tm, mask, tiV, hh_bf);

    gemm_mfma<EPI_RESID><<<dim3(8, 10), 256, 0, stream>>>(
        hh_bf, wo_t + (size_t)l * 512 * 512, bo + l*DD, nullptr, nullptr,
        h, tb, nullptr, MTOK, 512, 512);
    ln_kernel<<<MTOK, 256, 0, stream>>>(tb, g1 + l*DD, b1 + l*DD, h, h_bf);

    gemm_mfma<EPI_GELU><<<dim3(32, 10), 256, 0, stream>>>(
        h_bf, w1_t + (size_t)l * 2048 * 512, c1 + l*FFD, nullptr, nullptr,
        nullptr, nullptr, fb_bf, MTOK, FFD, 512);

    gemm_mfma<EPI_RESID><<<dim3(8, 10), 256, 0, stream>>>(
        fb_bf, w2_t + (size_t)l * 512 * 2048, c2 + l*DD, nullptr, nullptr,
        h, tb, nullptr, MTOK, 512, 2048);
    ln_kernel<<<MTOK, 256, 0, stream>>>(tb, g2 + l*DD, b2 + l*DD,
                                        (l == 1) ? out : h,
                                        (l == 1) ? nullptr : h_bf);
  }
}

// Round 5
// 147.898 us; speedup vs baseline: 4.7269x; 1.2801x over previous
//
#include <hip/hip_runtime.h>
#include <hip/hip_bf16.h>
#include <math.h>

#define SS 160
#define DD 512
#define HH 8
#define MTOK 640
#define FFD 2048
#define NTT 257   // T+1 time-embedding rows

typedef __attribute__((ext_vector_type(8))) short bfrag8;   // 8 bf16 = 4 VGPR
typedef __attribute__((ext_vector_type(4))) float facc4;    // 4 f32 accum
typedef unsigned short u16;

// XOR swizzle of 16B chunks within a 128B window (T2 pattern)
#define SWZ(row, cb) ((cb) ^ (((row)&7) << 4))

__device__ __forceinline__ void gload16(const void* g, void* l) {
  __builtin_amdgcn_global_load_lds(
      (const __attribute__((address_space(1))) void*)g,
      (__attribute__((address_space(3))) void*)l, 16, 0, 0);
}

// ================= prep_all: weight transposes + tiK conv + embed+LN0 ======
__device__ void wconv_body(const float* __restrict__ src,
                           __hip_bfloat16* __restrict__ dst,
                           int K, int N, int dls, int rowoff,
                           int l, int bx, int by, float (*tile)[65])
{
  src += (size_t)l * K * N;
  dst += (size_t)l * dls + (size_t)rowoff * K;
  int k0 = by * 64, n0 = bx * 64;
  int t = threadIdx.x;
  int r = t >> 2, c0 = (t & 3) * 16;
  #pragma unroll
  for (int j = 0; j < 16; j += 4) {
    float4 v4 = *(const float4*)&src[(size_t)(k0 + r) * N + n0 + c0 + j];
    tile[r][c0 + j + 0] = v4.x; tile[r][c0 + j + 1] = v4.y;
    tile[r][c0 + j + 2] = v4.z; tile[r][c0 + j + 3] = v4.w;
  }
  __syncthreads();
  union { u16 u[8]; uint4 v; } pk;
  #pragma unroll
  for (int half = 0; half < 2; ++half) {
    #pragma unroll
    for (int j = 0; j < 8; ++j) {
      __hip_bfloat16 hb = __float2bfloat16(tile[c0 + half * 8 + j][r]);
      pk.u[j] = *reinterpret_cast<u16*>(&hb);
    }
    *(uint4*)&dst[(size_t)(n0 + r) * K + k0 + c0 + half * 8] = pk.v;
  }
}

__global__ __launch_bounds__(256) void prep_all(
    const float* __restrict__ Wq, const float* __restrict__ Wk,
    const float* __restrict__ Wv, const float* __restrict__ Wo,
    const float* __restrict__ W1, const float* __restrict__ W2,
    const float* __restrict__ tiK,
    __hip_bfloat16* __restrict__ wqkv, __hip_bfloat16* __restrict__ wo_t,
    __hip_bfloat16* __restrict__ w1_t, __hip_bfloat16* __restrict__ w2_t,
    __hip_bfloat16* __restrict__ tikb,
    const int* __restrict__ x, const int* __restrict__ stamp,
    const float* __restrict__ tok, const float* __restrict__ month,
    const float* __restrict__ day, const float* __restrict__ g0,
    const float* __restrict__ b0, float* __restrict__ h,
    __hip_bfloat16* __restrict__ hb)
{
  __shared__ float tile[64][65];
  __shared__ float ssh[4], qsh[4];
  int idx = blockIdx.x;
  int tid = threadIdx.x;

  if (idx < 1536) {
    if (idx < 384) {
      int grp = idx / 128, r = idx % 128;
      int l = r / 64, t = r % 64;
      const float* src = grp == 0 ? Wq : (grp == 1 ? Wk : Wv);
      wconv_body(src, wqkv, 512, 512, 1536 * 512, 512 * grp, l, t % 8, t / 8, tile);
    } else if (idx < 512) {
      int r = idx - 384; int l = r / 64, t = r % 64;
      wconv_body(Wo, wo_t, 512, 512, 512 * 512, 0, l, t % 8, t / 8, tile);
    } else if (idx < 1024) {
      int r = idx - 512; int l = r / 256, t = r % 256;
      wconv_body(W1, w1_t, 512, 2048, 2048 * 512, 0, l, t % 32, t / 32, tile);
    } else {
      int r = idx - 1024; int l = r / 256, t = r % 256;
      wconv_body(W2, w2_t, 2048, 512, 512 * 2048, 0, l, t % 8, t / 8, tile);
    }
  } else if (idx < 1665) {
    int i = (idx - 1536) * 256 + tid;
    if (i < NTT * DD / 4) {
      float4 v = *(const float4*)(tiK + (size_t)i * 4);
      union { u16 u[4]; uint2 w; } pk;
      __hip_bfloat16 h0 = __float2bfloat16(v.x), h1 = __float2bfloat16(v.y);
      __hip_bfloat16 h2 = __float2bfloat16(v.z), h3 = __float2bfloat16(v.w);
      pk.u[0] = *(u16*)&h0; pk.u[1] = *(u16*)&h1;
      pk.u[2] = *(u16*)&h2; pk.u[3] = *(u16*)&h3;
      *(uint2*)(tikb + (size_t)i * 4) = pk.w;
    }
  } else {
    int m = idx - 1665;
    int b = m / SS, s = m % SS, t = tid;
    int tokid = x[m];
    float v0 = tok[tokid * DD + t];
    float v1 = tok[tokid * DD + t + 256];
    if (s > 0) {
      int sidx = (b * (SS - 1) + (s - 1)) * 3;
      int mo = stamp[sidx + 0], dy = stamp[sidx + 1];
      v0 += month[mo * DD + t]       + day[dy * DD + t];
      v1 += month[mo * DD + t + 256] + day[dy * DD + t + 256];
    }
    float sum = v0 + v1, sq = v0 * v0 + v1 * v1;
    #pragma unroll
    for (int off = 1; off < 64; off <<= 1) {
      sum += __shfl_xor(sum, off);
      sq  += __shfl_xor(sq , off);
    }
    if ((t & 63) == 0) { ssh[t >> 6] = sum; qsh[t >> 6] = sq; }
    __syncthreads();
    float fsum = ssh[0] + ssh[1] + ssh[2] + ssh[3];
    float fsq  = qsh[0] + qsh[1] + qsh[2] + qsh[3];
    float u = fsum * (1.0f / 512.0f);
    float var = fsq * (1.0f / 512.0f) - u * u;
    float r = rsqrtf(var + 1e-12f);
    float y0 = g0[t]       * ((v0 - u) * r) + b0[t];
    float y1 = g0[t + 256] * ((v1 - u) * r) + b0[t + 256];
    h[m * DD + t]        = y0;  h[m * DD + t + 256]  = y1;
    hb[m * DD + t]       = __float2bfloat16(y0);
    hb[m * DD + t + 256] = __float2bfloat16(y1);
  }
}

// ---------------- LayerNorm ----------------
__global__ __launch_bounds__(256) void ln_kernel(
    const float* __restrict__ in, const float* __restrict__ g,
    const float* __restrict__ b, float* __restrict__ out,
    __hip_bfloat16* __restrict__ outb)
{
  int m = blockIdx.x; int t = threadIdx.x;
  float v0 = in[m*DD + t];
  float v1 = in[m*DD + t + 256];
  float sum = v0+v1, sq = v0*v0+v1*v1;
  #pragma unroll
  for (int off=1; off<64; off<<=1) {
    sum += __shfl_xor(sum, off);
    sq  += __shfl_xor(sq , off);
  }
  __shared__ float ssh[4], qsh[4];
  if ((t&63)==0) { ssh[t>>6]=sum; qsh[t>>6]=sq; }
  __syncthreads();
  float fsum = ssh[0]+ssh[1]+ssh[2]+ssh[3];
  float fsq  = qsh[0]+qsh[1]+qsh[2]+qsh[3];
  float u = fsum * (1.0f/512.0f);
  float var = fsq * (1.0f/512.0f) - u*u;
  float r = rsqrtf(var + 1e-12f);
  float y0 = g[t]    *((v0-u)*r) + b[t];
  float y1 = g[t+256]*((v1-u)*r) + b[t+256];
  out[m*DD+t]     = y0;
  out[m*DD+t+256] = y1;
  if (outb) {
    outb[m*DD+t]     = __float2bfloat16(y0);
    outb[m*DD+t+256] = __float2bfloat16(y1);
  }
}

// ========== pipelined MFMA GEMM: C[M,N] = A[M,K] @ Bt[N,K]^T + bias ========
#define EPI_RESID 1
#define EPI_GELU 2
#define EPI_QKV 3

template<int EPI, int K>
__global__ __launch_bounds__(256) void gemm_ck(
    const __hip_bfloat16* __restrict__ A,   // [M][K]
    const __hip_bfloat16* __restrict__ Bt,  // [N][K]
    const float* __restrict__ bias,
    const float* __restrict__ bias2,   // EPI_QKV only
    const float* __restrict__ bias3,   // EPI_QKV only
    const float* __restrict__ resid,   // EPI_RESID only
    float* __restrict__ Cf,
    __hip_bfloat16* __restrict__ Cb,
    int N)
{
  constexpr int KC = 128;
  constexpr int NCH = K / KC;
  __shared__ u16 As[2][64 * KC];   // 2 x 16 KB
  __shared__ u16 Bs[2][64 * KC];
  const int tid = threadIdx.x, wv = tid >> 6, lane = tid & 63;
  const int m0 = blockIdx.y * 64, n0 = blockIdx.x * 64;
  const int wr = wv >> 1, wc = wv & 1;
  const int fr = lane & 15, fks = lane >> 4;

  const int ldsq = (wv * 4) * 1024;          // this wave's quarter
  const int off0 = ldsq + lane * 16;

  #define STAGE(c, buf) do {                                                  \
    _Pragma("unroll")                                                         \
    for (int i_ = 0; i_ < 4; ++i_) {                                          \
      int ldso = ldsq + i_ * 1024;                                            \
      int off = off0 + i_ * 1024;                                             \
      int r_ = off >> 8;                                                      \
      int p_ = off & 255;                                                     \
      int ps_ = p_ ^ ((r_ & 7) << 4);                                         \
      gload16((const char*)A  + ((size_t)(m0 + r_) * K + (c) * KC) * 2 + ps_, \
              (char*)&As[buf][0] + ldso);                                     \
      gload16((const char*)Bt + ((size_t)(n0 + r_) * K + (c) * KC) * 2 + ps_, \
              (char*)&Bs[buf][0] + ldso);                                     \
    }                                                                         \
  } while (0)

  facc4 acc[2][2] = {};
  STAGE(0, 0);
  STAGE(1, 1);

  #pragma unroll
  for (int c = 0; c < NCH; ++c) {
    if (c + 1 < NCH) asm volatile("s_waitcnt vmcnt(8)\n\ts_barrier" ::: "memory");
    else             asm volatile("s_waitcnt vmcnt(0)\n\ts_barrier" ::: "memory");
    const char* ab = (const char*)&As[c & 1][0];
    const char* bb = (const char*)&Bs[c & 1][0];
    #pragma unroll
    for (int ks = 0; ks < 4; ++ks) {
      bfrag8 af[2], bfv[2];
      #pragma unroll
      for (int mf = 0; mf < 2; ++mf) {
        int rA = wr * 32 + mf * 16 + fr;
        af[mf] = *(const bfrag8*)(ab + rA * 256 + SWZ(rA, ks * 64 + fks * 16));
      }
      #pragma unroll
      for (int nf = 0; nf < 2; ++nf) {
        int rB = wc * 32 + nf * 16 + fr;
        bfv[nf] = *(const bfrag8*)(bb + rB * 256 + SWZ(rB, ks * 64 + fks * 16));
      }
      #pragma unroll
      for (int mf = 0; mf < 2; ++mf)
        #pragma unroll
        for (int nf = 0; nf < 2; ++nf)
          acc[mf][nf] = __builtin_amdgcn_mfma_f32_16x16x32_bf16(
              af[mf], bfv[nf], acc[mf][nf], 0, 0, 0);
    }
    asm volatile("s_barrier" ::: "memory");
    if (c + 2 < NCH) STAGE(c + 2, c & 1);
  }
  #undef STAGE

  #pragma unroll
  for (int mf = 0; mf < 2; ++mf) {
    #pragma unroll
    for (int nf = 0; nf < 2; ++nf) {
      int col = n0 + wc * 32 + nf * 16 + fr;
      float bb;
      if (EPI == EPI_QKV)
        bb = col < 512 ? bias[col] : (col < 1024 ? bias2[col - 512] : bias3[col - 1024]);
      else
        bb = bias[col];
      #pragma unroll
      for (int j = 0; j < 4; ++j) {
        int row = m0 + wr * 32 + mf * 16 + fks * 4 + j;
        float c = acc[mf][nf][j] + bb;
        if (EPI == EPI_RESID) {
          c += resid[(size_t)row * N + col];
          Cf[(size_t)row * N + col] = c;
        } else {
          if (EPI == EPI_GELU) c = 0.5f * c * (1.0f + erff(c * 0.70710678118654752f));
          Cb[(size_t)row * N + col] = __float2bfloat16(c);
        }
      }
    }
  }
}

// ========== merged Sk = QK^T  and  G = Q . tiK^T  (one dispatch) ===========
__global__ __launch_bounds__(256) void skg_kernel(
    const __hip_bfloat16* __restrict__ qkv,
    const __hip_bfloat16* __restrict__ tikb,
    float* __restrict__ Sk, float* __restrict__ G)
{
  __shared__ u16 As[64 * 64];
  __shared__ u16 Bs[64 * 64];
  const int tid = threadIdx.x;
  const int wid = tid >> 6, lane = tid & 63;
  const int wr = wid >> 1, wc = wid & 1;
  const int fr = lane & 15, fks = lane >> 4;
  const int sr = tid >> 2, sc = (tid & 3) * 16;
  const int swz0 = sr * 128 + SWZ(sr, sc * 2);
  const int swz1 = sr * 128 + SWZ(sr, sc * 2 + 16);
  int idx = blockIdx.x;

  if (idx < 288) {
    const int z = idx / 9, rem = idx % 9;
    const int m0 = (rem / 3) * 64, n0 = (rem % 3) * 64;
    const int b = z >> 3, h = z & 7;
    const __hip_bfloat16* Aq = qkv + (size_t)b * SS * 1536 + h * 64;
    const __hip_bfloat16* Bt = qkv + (size_t)b * SS * 1536 + 512 + h * 64;
    float* C = Sk + (size_t)z * SS * SS;
    const int ar = min(m0 + sr, SS - 1), br = min(n0 + sr, SS - 1);
    uint4 av0 = *(const uint4*)(Aq + (size_t)ar * 1536 + sc);
    uint4 av1 = *(const uint4*)(Aq + (size_t)ar * 1536 + sc + 8);
    uint4 bv0 = *(const uint4*)(Bt + (size_t)br * 1536 + sc);
    uint4 bv1 = *(const uint4*)(Bt + (size_t)br * 1536 + sc + 8);
    *(uint4*)((char*)As + swz0) = av0;
    *(uint4*)((char*)As + swz1) = av1;
    *(uint4*)((char*)Bs + swz0) = bv0;
    *(uint4*)((char*)Bs + swz1) = bv1;
    __syncthreads();
    facc4 acc[2][2] = {};
    #pragma unroll
    for (int ks = 0; ks < 2; ++ks) {
      bfrag8 af[2], bfv[2];
      #pragma unroll
      for (int mf = 0; mf < 2; ++mf) {
        int rA = wr * 32 + mf * 16 + fr;
        af[mf] = *(const bfrag8*)((const char*)As + rA * 128 + SWZ(rA, 64 * ks + 16 * fks));
      }
      #pragma unroll
      for (int nf = 0; nf < 2; ++nf) {
        int rB = wc * 32 + nf * 16 + fr;
        bfv[nf] = *(const bfrag8*)((const char*)Bs + rB * 128 + SWZ(rB, 64 * ks + 16 * fks));
      }
      #pragma unroll
      for (int mf = 0; mf < 2; ++mf)
        #pragma unroll
        for (int nf = 0; nf < 2; ++nf)
          acc[mf][nf] = __builtin_amdgcn_mfma_f32_16x16x32_bf16(
              af[mf], bfv[nf], acc[mf][nf], 0, 0, 0);
    }
    #pragma unroll
    for (int mf = 0; mf < 2; ++mf)
      #pragma unroll
      for (int nf = 0; nf < 2; ++nf) {
        int col = n0 + wc * 32 + nf * 16 + fr;
        #pragma unroll
        for (int j = 0; j < 4; ++j) {
          int row = m0 + wr * 32 + mf * 16 + fks * 4 + j;
          if (row < SS && col < SS) C[row * SS + col] = acc[mf][nf][j];
        }
      }
  } else {
    int i2 = idx - 288;
    const int nb = i2 % 5, mb = (i2 / 5) % 10, h = i2 / 50;
    const int m0 = mb * 64, n0 = nb * 64;
    const __hip_bfloat16* Aq = qkv + h * 64;
    const __hip_bfloat16* Bt = tikb + h * 64;
    const int br = min(n0 + sr, NTT - 1);
    uint4 av0 = *(const uint4*)(Aq + (size_t)(m0 + sr) * 1536 + sc);
    uint4 av1 = *(const uint4*)(Aq + (size_t)(m0 + sr) * 1536 + sc + 8);
    uint4 bv0 = *(const uint4*)(Bt + (size_t)br * 512 + sc);
    uint4 bv1 = *(const uint4*)(Bt + (size_t)br * 512 + sc + 8);
    *(uint4*)((char*)As + swz0) = av0;
    *(uint4*)((char*)As + swz1) = av1;
    *(uint4*)((char*)Bs + swz0) = bv0;
    *(uint4*)((char*)Bs + swz1) = bv1;
    __syncthreads();
    facc4 acc[2][2] = {};
    #pragma unroll
    for (int ks = 0; ks < 2; ++ks) {
      bfrag8 af[2], bfv[2];
      #pragma unroll
      for (int mf = 0; mf < 2; ++mf) {
        int rA = wr * 32 + mf * 16 + fr;
        af[mf] = *(const bfrag8*)((const char*)As + rA * 128 + SWZ(rA, 64 * ks + 16 * fks));
      }
      #pragma unroll
      for (int nf = 0; nf < 2; ++nf) {
        int rB = wc * 32 + nf * 16 + fr;
        bfv[nf] = *(const bfrag8*)((const char*)Bs + rB * 128 + SWZ(rB, 64 * ks + 16 * fks));
      }
      #pragma unroll
      for (int mf = 0; mf < 2; ++mf)
        #pragma unroll
        for (int nf = 0; nf < 2; ++nf)
          acc[mf][nf] = __builtin_amdgcn_mfma_f32_16x16x32_bf16(
              af[mf], bfv[nf], acc[mf][nf], 0, 0, 0);
    }
    #pragma unroll
    for (int mf = 0; mf < 2; ++mf)
      #pragma unroll
      for (int nf = 0; nf < 2; ++nf) {
        int col = n0 + wc * 32 + nf * 16 + fr;
        #pragma unroll
        for (int j = 0; j < 4; ++j) {
          int row = m0 + wr * 32 + mf * 16 + fks * 4 + j;
          if (col < NTT)
            G[((size_t)h * MTOK + row) * NTT + col] = acc[mf][nf][j];
        }
      }
  }
}

// ---------------- attention: softmax + PV (scores precomputed) ------------
__global__ __launch_bounds__(256) void attn2(
    const __hip_bfloat16* __restrict__ qkv,
    const float* __restrict__ Sk, const float* __restrict__ G,
    const int* __restrict__ tm, const int* __restrict__ mask,
    const float* __restrict__ tiV, __hip_bfloat16* __restrict__ hh)
{
  const int h = blockIdx.y, b = blockIdx.z;
  const int ib0 = blockIdx.x * 8;
  const int tid = threadIdx.x, wv = tid >> 6, lane = tid & 63;
  __shared__ float P[8][176];
  __shared__ int tmsh[8][176];

  float rinvs[2];
  #pragma unroll
  for (int rr = 0; rr < 2; ++rr) {
    const int r = wv * 2 + rr, i = ib0 + r, m = b * SS + i;
    const float* Grow = G + ((size_t)h * MTOK + m) * NTT;
    const float* Srow = Sk + ((size_t)(b * 8 + h) * SS + i) * SS;
    const int* tmrow = tm + (size_t)m * SS;
    float sv[3];
    float mx = -1e30f;
    #pragma unroll
    for (int g = 0; g < 3; ++g) {
      int j = lane + g * 64;
      if (j < SS) {
        int t = tmrow[j];
        tmsh[r][j] = t;
        float s = (Srow[j] + Grow[t]) * 0.125f
                + 10000.0f * (1.0f - (float)mask[b * SS + j]);
        sv[g] = s; mx = fmaxf(mx, s);
      } else sv[g] = -1e30f;
    }
    #pragma unroll
    for (int off = 1; off < 64; off <<= 1) mx = fmaxf(mx, __shfl_xor(mx, off));
    float sum = 0.f;
    #pragma unroll
    for (int g = 0; g < 3; ++g) {
      int j = lane + g * 64;
      if (j < SS) { float p = expf(sv[g] - mx); P[r][j] = p; sum += p; }
    }
    #pragma unroll
    for (int off = 1; off < 64; off <<= 1) sum += __shfl_xor(sum, off);
    rinvs[rr] = 1.0f / sum;
  }

  const int r0 = wv * 2, r1 = r0 + 1;
  const int i0 = ib0 + r0, i1 = ib0 + r1;
  const __hip_bfloat16* vbase = qkv + (size_t)b * SS * 1536 + 1024 + h * 64 + lane;
  const float* tvbase = tiV + h * 64 + lane;
  float acc0 = 0.f, acc1 = 0.f;
  #pragma unroll 4
  for (int j = 0; j < SS; ++j) {
    float vv = __bfloat162float(vbase[(size_t)j * 1536]);
    float a0 = P[r0][j], a1 = P[r1][j];
    int t0 = tmsh[r0][j], t1 = tmsh[r1][j];
    acc0 += a0 * (vv + tvbase[(size_t)t0 * 512]);
    acc1 += a1 * (vv + tvbase[(size_t)t1 * 512]);
  }
  hh[((size_t)(b * SS) + i0) * DD + h * 64 + lane] = __float2bfloat16(acc0 * rinvs[0]);
  hh[((size_t)(b * SS) + i1) * DD + h * 64 + lane] = __float2bfloat16(acc1 * rinvs[1]);
}

// ---------------- launch ----------------
extern "C" void kernel_launch(void* const* d_in, const int* in_sizes, int n_in,
                              void* d_out, int out_size, void* d_ws, size_t ws_size,
                              hipStream_t stream) {
  const int*   x     = (const int*)d_in[0];
  const int*   stamp = (const int*)d_in[1];
  const int*   mask  = (const int*)d_in[2];
  const int*   tm    = (const int*)d_in[3];
  const float* tok   = (const float*)d_in[4];
  const float* month = (const float*)d_in[5];
  const float* day   = (const float*)d_in[6];
  const float* tiK   = (const float*)d_in[7];
  const float* tiV   = (const float*)d_in[8];
  const float* g0    = (const float*)d_in[9];
  const float* b0    = (const float*)d_in[10];
  const float* Wq    = (const float*)d_in[11];
  const float* bq    = (const float*)d_in[12];
  const float* Wk    = (const float*)d_in[13];
  const float* bk    = (const float*)d_in[14];
  const float* Wv    = (const float*)d_in[15];
  const float* bv    = (const float*)d_in[16];
  const float* Wo    = (const float*)d_in[17];
  const float* bo    = (const float*)d_in[18];
  const float* g1    = (const float*)d_in[19];
  const float* b1    = (const float*)d_in[20];
  const float* W1    = (const float*)d_in[21];
  const float* c1    = (const float*)d_in[22];
  const float* W2    = (const float*)d_in[23];
  const float* c2    = (const float*)d_in[24];
  const float* g2    = (const float*)d_in[25];
  const float* b2    = (const float*)d_in[26];

  float* out = (float*)d_out;
  const size_t NT = (size_t)MTOK * DD;

  char* p = (char*)d_ws;
  float* h    = (float*)p;  p += NT * 4;
  float* tb   = (float*)p;  p += NT * 4;
  float* Skb  = (float*)p;  p += (size_t)32 * SS * SS * 4;
  float* Gb   = (float*)p;  p += (size_t)HH * MTOK * NTT * 4;
  __hip_bfloat16* h_bf   = (__hip_bfloat16*)p;  p += NT * 2;
  __hip_bfloat16* hh_bf  = (__hip_bfloat16*)p;  p += NT * 2;
  __hip_bfloat16* fb_bf  = (__hip_bfloat16*)p;  p += (size_t)MTOK * FFD * 2;
  __hip_bfloat16* qkv_bf = (__hip_bfloat16*)p;  p += (size_t)MTOK * 1536 * 2;
  __hip_bfloat16* tikb   = (__hip_bfloat16*)p;  p += (size_t)NTT * DD * 2;
  __hip_bfloat16* wqkv   = (__hip_bfloat16*)p;  p += (size_t)2 * 1536 * 512 * 2;
  __hip_bfloat16* wo_t   = (__hip_bfloat16*)p;  p += (size_t)2 * 512 * 512 * 2;
  __hip_bfloat16* w1_t   = (__hip_bfloat16*)p;  p += (size_t)2 * 2048 * 512 * 2;
  __hip_bfloat16* w2_t   = (__hip_bfloat16*)p;  p += (size_t)2 * 512 * 2048 * 2;

  prep_all<<<2305, 256, 0, stream>>>(Wq, Wk, Wv, Wo, W1, W2, tiK,
                                     wqkv, wo_t, w1_t, w2_t, tikb,
                                     x, stamp, tok, month, day, g0, b0, h, h_bf);

  for (int l = 0; l < 2; ++l) {
    gemm_ck<EPI_QKV, 512><<<dim3(24, 10), 256, 0, stream>>>(
        h_bf, wqkv + (size_t)l * 1536 * 512, bq + l*DD, bk + l*DD, bv + l*DD,
        nullptr, nullptr, qkv_bf, 1536);

    skg_kernel<<<688, 256, 0, stream>>>(qkv_bf, tikb, Skb, Gb);

    attn2<<<dim3(20, 8, 4), 256, 0, stream>>>(qkv_bf, Skb, Gb, tm, mask, tiV, hh_bf);

    gemm_ck<EPI_RESID, 512><<<dim3(8, 10), 256, 0, stream>>>(
        hh_bf, wo_t + (size_t)l * 512 * 512, bo + l*DD, nullptr, nullptr,
        h, tb, nullptr, 512);
    ln_kernel<<<MTOK, 256, 0, stream>>>(tb, g1 + l*DD, b1 + l*DD, h, h_bf);

    gemm_ck<EPI_GELU, 512><<<dim3(32, 10), 256, 0, stream>>>(
        h_bf, w1_t + (size_t)l * 2048 * 512, c1 + l*FFD, nullptr, nullptr,
        nullptr, nullptr, fb_bf, 2048);

    gemm_ck<EPI_RESID, 2048><<<dim3(8, 10), 256, 0, stream>>>(
        fb_bf, w2_t + (size_t)l * 512 * 2048, c2 + l*DD, nullptr, nullptr,
        h, tb, nullptr, 512);
    ln_kernel<<<MTOK, 256, 0, stream>>>(tb, g2 + l*DD, b2 + l*DD,
                                        (l == 1) ? out : h,
                                        (l == 1) ? nullptr : h_bf);
  }
}